// Round 6
// baseline (314.438 us; speedup 1.0000x reference)
//
#include <hip/hip_runtime.h>
#include <hip/hip_bf16.h>

// MoE: B=2,S=2048 -> T=4096 tokens, H=1024, F=2048, E=8, TOPK=2
#define TT 4096
#define HH 1024
#define FF 2048
#define EE 8
#define NCONV 8192   // EE*FF*HH / (256*8)
#define CONVB 3072   // persistent conv blocks in front_kernel

typedef short short8_t __attribute__((ext_vector_type(8)));
typedef float f32x4 __attribute__((ext_vector_type(4)));

__device__ __forceinline__ unsigned short f2b(float f) {
  union { float f; unsigned u; } v; v.f = f;
  return (unsigned short)((v.u + 0x7fffu + ((v.u >> 16) & 1u)) >> 16);  // RNE
}

__device__ __forceinline__ short8_t pack8(float4 a, float4 b) {
  short8_t r;
  r[0] = (short)f2b(a.x); r[1] = (short)f2b(a.y);
  r[2] = (short)f2b(a.z); r[3] = (short)f2b(a.w);
  r[4] = (short)f2b(b.x); r[5] = (short)f2b(b.y);
  r[6] = (short)f2b(b.z); r[7] = (short)f2b(b.w);
  return r;
}

__device__ __forceinline__ void gload16(const unsigned short* g, unsigned short* l) {
  __builtin_amdgcn_global_load_lds(
      (const __attribute__((address_space(1))) void*)g,
      (__attribute__((address_space(3))) void*)l, 16, 0, 0);
}

__device__ __forceinline__ void conv_body(const float* __restrict__ src,
                                          unsigned short* __restrict__ dst,
                                          int b, int tid) {
  size_t i = ((size_t)b * 256 + tid) * 8;
  float4 a = *reinterpret_cast<const float4*>(src + i);
  float4 c = *reinterpret_cast<const float4*>(src + i + 4);
  *reinterpret_cast<short8_t*>(dst + i) = pack8(a, c);
}

// -------- Front: router (atomic-free) + grid-stride w1/w3[/w2] convs ------------
__global__ __launch_bounds__(256) void front_kernel(
    const float* __restrict__ x, const float* __restrict__ gw,
    const float* __restrict__ w1, const float* __restrict__ w3,
    const float* __restrict__ w2,
    float* __restrict__ out_logits, float* __restrict__ final_out,
    unsigned short* __restrict__ xbf,
    unsigned short* __restrict__ w1bf, unsigned short* __restrict__ w3bf,
    unsigned short* __restrict__ w2bf, int do_w2,
    int* __restrict__ sel01, float2* __restrict__ w01)
{
  int tid = threadIdx.x;
  int b = blockIdx.x;
  if (b >= TT) {
    int cb = b - TT;
    int total = do_w2 ? 3 * NCONV : 2 * NCONV;
    for (int w = cb; w < total; w += CONVB) {
      if (w < NCONV)          conv_body(w1, w1bf, w, tid);
      else if (w < 2 * NCONV) conv_body(w3, w3bf, w - NCONV, tid);
      else                    conv_body(w2, w2bf, w - 2 * NCONV, tid);
    }
    return;
  }
  int t = b;

  __shared__ float xs[HH];
  __shared__ float lg[EE];

  float4 v = reinterpret_cast<const float4*>(x + (size_t)t * HH)[tid];
  xs[tid * 4 + 0] = v.x; xs[tid * 4 + 1] = v.y;
  xs[tid * 4 + 2] = v.z; xs[tid * 4 + 3] = v.w;
  ushort4 b4;
  b4.x = f2b(v.x); b4.y = f2b(v.y); b4.z = f2b(v.z); b4.w = f2b(v.w);
  reinterpret_cast<ushort4*>(xbf + (size_t)t * HH)[tid] = b4;
  float4 z4; z4.x = z4.y = z4.z = z4.w = 0.f;
  reinterpret_cast<float4*>(final_out + (size_t)t * HH)[tid] = z4;
  __syncthreads();

  int lane = tid & 63, wv = tid >> 6;
  for (int e = wv; e < EE; e += 4) {
    float s = 0.f;
    const float* g = gw + (size_t)e * HH;
#pragma unroll
    for (int j = 0; j < HH / 64; ++j) s += xs[lane + j * 64] * g[lane + j * 64];
#pragma unroll
    for (int off = 32; off > 0; off >>= 1) s += __shfl_down(s, off);
    if (lane == 0) lg[e] = s;
  }
  __syncthreads();

  if (tid < 8) out_logits[(size_t)t * EE + tid] = lg[tid];
  if (tid == 0) {
    float l[EE];
#pragma unroll
    for (int e = 0; e < EE; ++e) l[e] = lg[e];
    int e0 = 0;
#pragma unroll
    for (int e = 1; e < EE; ++e) if (l[e] > l[e0]) e0 = e;
    int e1 = -1;
#pragma unroll
    for (int e = 0; e < EE; ++e) if (e != e0 && (e1 < 0 || l[e] > l[e1])) e1 = e;
    float p1 = expf(l[e1] - l[e0]);
    float w0 = 1.f / (1.f + p1);
    float w1v = p1 * w0;
    sel01[t] = e0 | (e1 << 8);
    w01[t] = make_float2(w0, w1v);
  }
}

// -------- Build: per-expert compacted token lists, atomic-free, deterministic ----
__global__ __launch_bounds__(256) void build_kernel(
    const int* __restrict__ sel01, const float2* __restrict__ w01,
    int* __restrict__ counts, int* __restrict__ tokidx, float* __restrict__ rww)
{
  int e = blockIdx.x;
  int tid = threadIdx.x, lane = tid & 63, wv = tid >> 6;
  __shared__ int wsum[4];
  int base = 0;
  for (int t0 = 0; t0 < TT; t0 += 256) {
    int t = t0 + tid;
    int s = sel01[t];
    int e0 = s & 255, e1 = (s >> 8) & 255;
    bool hit = (e0 == e) || (e1 == e);
    float w = 0.f;
    if (hit) { float2 ww = w01[t]; w = (e0 == e) ? ww.x : ww.y; }
    unsigned long long m = __ballot(hit);
    int wpre = __popcll(m & ((1ull << lane) - 1));
    if (lane == 63) wsum[wv] = wpre + (hit ? 1 : 0);
    __syncthreads();
    int wbase = base;
    for (int q = 0; q < wv; ++q) wbase += wsum[q];
    if (hit) {
      int pos = wbase + wpre;
      tokidx[e * TT + pos] = t;
      rww[e * TT + pos] = w;
    }
    base += wsum[0] + wsum[1] + wsum[2] + wsum[3];
    __syncthreads();
  }
  if (tid == 0) counts[e] = base;
}

// -------- Standalone conv for w2 (fallback when ws too small: after up_gate) ----
__global__ __launch_bounds__(256) void conv_kernel(
    const float* __restrict__ src, unsigned short* __restrict__ dst)
{
  conv_body(src, dst, blockIdx.x, threadIdx.x);
}

// -------- Up-proj + gate: depth-2 prefetch, 3 bufs, LITERAL buffer indices -------
__global__ __launch_bounds__(256) void up_gate_kernel(
    const unsigned short* __restrict__ xbf,
    const unsigned short* __restrict__ w1bf, const unsigned short* __restrict__ w3bf,
    const int* __restrict__ counts, const int* __restrict__ tokidx,
    unsigned short* __restrict__ gated)
{
  int e = blockIdx.z;
  int n = counts[e];
  int row0 = blockIdx.y * 128;
  if (row0 >= n) return;
  int fbase = blockIdx.x * 64;

  int pe = 0;
  for (int q = 0; q < e; ++q) pe += (counts[q] + 127) & ~127;

  __shared__ unsigned short As[3][128 * 32];   // 3 x 8 KB
  __shared__ unsigned short B1s[3][64 * 32];   // 3 x 4 KB
  __shared__ unsigned short B3s[3][64 * 32];   // 3 x 4 KB

  int tid = threadIdx.x;
  int lane = tid & 63, wv = tid >> 6;
  int srow = wv * 16 + (lane >> 2);      // 0..63
  int skoff = (lane & 3) * 8;            // k-offset (elements)

  int r0 = min(row0 + srow, n - 1);
  int r1 = min(row0 + 64 + srow, n - 1);
  int t0 = tokidx[e * TT + r0];
  int t1 = tokidx[e * TT + r1];
  const unsigned short* ga0 = xbf + (size_t)t0 * HH + skoff;
  const unsigned short* ga1 = xbf + (size_t)t1 * HH + skoff;
  const unsigned short* gb1 = w1bf + ((size_t)e * FF + fbase + srow) * HH + skoff;
  const unsigned short* gb3 = w3bf + ((size_t)e * FF + fbase + srow) * HH + skoff;

  int wr = (wv >> 1) * 64, wc = (wv & 1) * 32;
  int fr = lane & 15, fk = (lane >> 4) * 8;

  f32x4 acc1[4][2], acc3[4][2];
#pragma unroll
  for (int m = 0; m < 4; ++m)
#pragma unroll
    for (int nn = 0; nn < 2; ++nn) { acc1[m][nn] = (f32x4)0.f; acc3[m][nn] = (f32x4)0.f; }

#define UG_STAGE(KK, BB) do {                                  \
    gload16(ga0 + (KK), &As[BB][wv * 512]);                    \
    gload16(ga1 + (KK), &As[BB][2048 + wv * 512]);             \
    gload16(gb1 + (KK), &B1s[BB][wv * 512]);                   \
    gload16(gb3 + (KK), &B3s[BB][wv * 512]); } while (0)

#define UG_COMPUTE(CB) do {                                                                   \
    short8_t a[4], b1f[2], b3f[2];                                                            \
    _Pragma("unroll") for (int m = 0; m < 4; ++m)                                             \
      a[m] = *reinterpret_cast<const short8_t*>(&As[CB][(wr + m * 16 + fr) * 32 + fk]);       \
    _Pragma("unroll") for (int nn = 0; nn < 2; ++nn) {                                        \
      b1f[nn] = *reinterpret_cast<const short8_t*>(&B1s[CB][(wc + nn * 16 + fr) * 32 + fk]);  \
      b3f[nn] = *reinterpret_cast<const short8_t*>(&B3s[CB][(wc + nn * 16 + fr) * 32 + fk]);  \
    }                                                                                         \
    _Pragma("unroll") for (int m = 0; m < 4; ++m)                                             \
      _Pragma("unroll") for (int nn = 0; nn < 2; ++nn) {                                      \
        acc1[m][nn] = __builtin_amdgcn_mfma_f32_16x16x32_bf16(a[m], b1f[nn], acc1[m][nn], 0, 0, 0); \
        acc3[m][nn] = __builtin_amdgcn_mfma_f32_16x16x32_bf16(a[m], b3f[nn], acc3[m][nn], 0, 0, 0); \
      } } while (0)

#define UG_STEP(CB, SB, TCUR, DOSTAGE, WAITN) do {             \
    asm volatile("s_waitcnt vmcnt(" #WAITN ")" ::: "memory");  \
    __builtin_amdgcn_s_barrier();                              \
    __builtin_amdgcn_sched_barrier(0);                         \
    if (DOSTAGE) UG_STAGE(((TCUR) + 2) * 32, SB);              \
    UG_COMPUTE(CB); } while (0)

  // NK = 32 K-tiles. Depth-2: tiles t, t+1 always in flight.
  UG_STAGE(0, 0);
  UG_STAGE(32, 1);
  for (int tb = 0; tb < 30; tb += 3) {
    UG_STEP(0, 2, tb + 0, 1, 4);
    UG_STEP(1, 0, tb + 1, 1, 4);
    UG_STEP(2, 1, tb + 2, 1, 4);
  }
  UG_STEP(0, 2, 30, 0, 4);
  UG_STEP(1, 0, 31, 0, 0);
#undef UG_STAGE
#undef UG_COMPUTE
#undef UG_STEP

  // epilogue: gated = silu(h1)*h3 -> bf16 (pad rows exact zeros discarded later)
  size_t gbase = ((size_t)pe + row0) * FF + fbase;
#pragma unroll
  for (int m = 0; m < 4; ++m) {
#pragma unroll
    for (int nn = 0; nn < 2; ++nn) {
      f32x4 h1v = acc1[m][nn], h3v = acc3[m][nn];
#pragma unroll
      for (int j = 0; j < 4; ++j) {
        float z = h1v[j];
        float val = (z / (1.f + expf(-z))) * h3v[j];
        int r = wr + m * 16 + (lane >> 4) * 4 + j;
        int c = wc + nn * 16 + fr;
        gated[gbase + (size_t)r * FF + c] = f2b(val);
      }
    }
  }
}

// -------- Down-proj + weighted scatter: depth-2, 3 bufs, LITERAL indices ---------
__global__ __launch_bounds__(256) void down_kernel(
    const unsigned short* __restrict__ gated,
    const unsigned short* __restrict__ w2bf,
    const int* __restrict__ counts, const int* __restrict__ tokidx,
    const float* __restrict__ rww,
    float* __restrict__ final_out)
{
  int e = blockIdx.z;
  int n = counts[e];
  int row0 = blockIdx.y * 128;
  if (row0 >= n) return;
  int hbase = blockIdx.x * 128;
  int valid = min(128, n - row0);

  int pe = 0;
  for (int q = 0; q < e; ++q) pe += (counts[q] + 127) & ~127;

  __shared__ unsigned short As[3][128 * 32];   // 3 x 8 KB
  __shared__ unsigned short Bs[3][128 * 32];   // 3 x 8 KB

  int tid = threadIdx.x;
  int lane = tid & 63, wv = tid >> 6;
  int srow = wv * 16 + (lane >> 2);
  int skoff = (lane & 3) * 8;

  const unsigned short* ga0 = gated + ((size_t)pe + row0 + srow) * FF + skoff;
  const unsigned short* ga1 = ga0 + (size_t)64 * FF;
  const unsigned short* gb0 = w2bf + ((size_t)e * HH + hbase + srow) * FF + skoff;
  const unsigned short* gb1 = gb0 + (size_t)64 * FF;

  int wr = (wv >> 1) * 64, wc = (wv & 1) * 64;
  int fr = lane & 15, fk = (lane >> 4) * 8;

  f32x4 acc[4][4];
#pragma unroll
  for (int m = 0; m < 4; ++m)
#pragma unroll
    for (int nn = 0; nn < 4; ++nn) acc[m][nn] = (f32x4)0.f;

#define DN_STAGE(KK, BB) do {                                  \
    gload16(ga0 + (KK), &As[BB][wv * 512]);                    \
    gload16(ga1 + (KK), &As[BB][2048 + wv * 512]);             \
    gload16(gb0 + (KK), &Bs[BB][wv * 512]);                    \
    gload16(gb1 + (KK), &Bs[BB][2048 + wv * 512]); } while (0)

#define DN_COMPUTE(CB) do {                                                                  \
    short8_t a[4], bf[4];                                                                    \
    _Pragma("unroll") for (int m = 0; m < 4; ++m)                                            \
      a[m] = *reinterpret_cast<const short8_t*>(&As[CB][(wr + m * 16 + fr) * 32 + fk]);      \
    _Pragma("unroll") for (int nn = 0; nn < 4; ++nn)                                         \
      bf[nn] = *reinterpret_cast<const short8_t*>(&Bs[CB][(wc + nn * 16 + fr) * 32 + fk]);   \
    _Pragma("unroll") for (int m = 0; m < 4; ++m)                                            \
      _Pragma("unroll") for (int nn = 0; nn < 4; ++nn)                                       \
        acc[m][nn] = __builtin_amdgcn_mfma_f32_16x16x32_bf16(a[m], bf[nn], acc[m][nn], 0, 0, 0); \
  } while (0)

#define DN_STEP(CB, SB, TCUR, DOSTAGE, WAITN) do {             \
    asm volatile("s_waitcnt vmcnt(" #WAITN ")" ::: "memory");  \
    __builtin_amdgcn_s_barrier();                              \
    __builtin_amdgcn_sched_barrier(0);                         \
    if (DOSTAGE) DN_STAGE(((TCUR) + 2) * 32, SB);              \
    DN_COMPUTE(CB); } while (0)

  // NK = 64 K-tiles.
  DN_STAGE(0, 0);
  DN_STAGE(32, 1);
  for (int tb = 0; tb < 60; tb += 3) {
    DN_STEP(0, 2, tb + 0, 1, 4);
    DN_STEP(1, 0, tb + 1, 1, 4);
    DN_STEP(2, 1, tb + 2, 1, 4);
  }
  DN_STEP(0, 2, 60, 1, 4);   // stage tile 62 -> buf 2
  DN_STEP(1, 0, 61, 1, 4);   // stage tile 63 -> buf 0
  DN_STEP(2, 1, 62, 0, 4);
  DN_STEP(0, 1, 63, 0, 0);
#undef DN_STAGE
#undef DN_COMPUTE
#undef DN_STEP

  // epilogue: final[t, h] += rw * out  (2 commutative f32 adds per element)
#pragma unroll
  for (int m = 0; m < 4; ++m) {
    int rbase = wr + m * 16 + (lane >> 4) * 4;
#pragma unroll
    for (int j = 0; j < 4; ++j) {
      int r = rbase + j;
      if (r < valid) {
        int t = tokidx[e * TT + row0 + r];
        float w = rww[e * TT + row0 + r];
#pragma unroll
        for (int nn = 0; nn < 4; ++nn) {
          int c = hbase + wc + nn * 16 + fr;
          atomicAdd(&final_out[(size_t)t * HH + c], w * acc[m][nn][j]);
        }
      }
    }
  }
}

extern "C" void kernel_launch(void* const* d_in, const int* in_sizes, int n_in,
                              void* d_out, int out_size, void* d_ws, size_t ws_size,
                              hipStream_t stream) {
  const float* x  = (const float*)d_in[0];   // [T, H]
  const float* gw = (const float*)d_in[1];   // [E, H]
  const float* w1 = (const float*)d_in[2];   // [E, F, H]
  const float* w2 = (const float*)d_in[3];   // [E, H, F]
  const float* w3 = (const float*)d_in[4];   // [E, F, H]

  float* final_out  = (float*)d_out;                       // [T, H]
  float* out_logits = final_out + (size_t)TT * HH;         // [T, E]

  char* ws = (char*)d_ws;
  int*    counts = (int*)(ws + 0);                            // 64 B
  int*    sel01  = (int*)(ws + 1024);                         // 16384
  float2* w01    = (float2*)(ws + 20480);                     // 32768
  int*    tokidx = (int*)(ws + 53248);                        // 131072
  float*  rww    = (float*)(ws + 184320);                     // 131072
  unsigned short* xbf   = (unsigned short*)(ws + 315392);     // 8388608
  unsigned short* w1bf  = (unsigned short*)(ws + 8704000);    // 33554432
  unsigned short* w3bf  = (unsigned short*)(ws + 42258432);   // 33554432
  unsigned short* gated = (unsigned short*)(ws + 75812864);   // 37748736
  const size_t base_end = 113561600;
  bool big = ws_size >= base_end + 33554432;                  // +32MB for w2bf
  unsigned short* w2bf = big ? (unsigned short*)(ws + base_end) : w1bf;

  front_kernel<<<TT + CONVB, 256, 0, stream>>>(
      x, gw, w1, w3, w2, out_logits, final_out, xbf, w1bf, w3bf, w2bf,
      big ? 1 : 0, sel01, w01);
  build_kernel<<<EE, 256, 0, stream>>>(sel01, w01, counts, tokidx, rww);
  up_gate_kernel<<<dim3(FF / 64, TT / 128, EE), 256, 0, stream>>>(
      xbf, w1bf, w3bf, counts, tokidx, gated);
  if (!big) conv_kernel<<<NCONV, 256, 0, stream>>>(w2, w1bf);
  down_kernel<<<dim3(HH / 128, TT / 128, EE), 256, 0, stream>>>(
      gated, w2bf, counts, tokidx, rww, final_out);
}

// Round 7
// 266.163 us; speedup vs baseline: 1.1814x; 1.1814x over previous
//
#include <hip/hip_runtime.h>
#include <hip/hip_bf16.h>

// MoE: B=2,S=2048 -> T=4096 tokens, H=1024, F=2048, E=8, TOPK=2
#define TT 4096
#define HH 1024
#define FF 2048
#define EE 8
#define NC32 2048   // EE*FF*HH / (256*32) conv chunks per weight tensor

typedef short short8_t __attribute__((ext_vector_type(8)));
typedef float f32x4 __attribute__((ext_vector_type(4)));

__device__ __forceinline__ unsigned short f2b(float f) {
  union { float f; unsigned u; } v; v.f = f;
  return (unsigned short)((v.u + 0x7fffu + ((v.u >> 16) & 1u)) >> 16);  // RNE
}

__device__ __forceinline__ void gload16(const unsigned short* g, unsigned short* l) {
  __builtin_amdgcn_global_load_lds(
      (const __attribute__((address_space(1))) void*)g,
      (__attribute__((address_space(3))) void*)l, 16, 0, 0);
}

// Batched-ILP f32->bf16 conv: 8 independent float4 loads in flight per thread.
// Chunk = 256 threads * 32 floats = 8192 elements.
__device__ __forceinline__ void conv_ilp(const float* __restrict__ src,
                                         unsigned short* __restrict__ dst,
                                         int c, int tid) {
  size_t base = (size_t)c * 8192 + tid * 4;
  float4 v[8];
#pragma unroll
  for (int j = 0; j < 8; ++j)
    v[j] = *reinterpret_cast<const float4*>(src + base + j * 1024);
#pragma unroll
  for (int j = 0; j < 8; ++j) {
    ushort4 b4;
    b4.x = f2b(v[j].x); b4.y = f2b(v[j].y); b4.z = f2b(v[j].z); b4.w = f2b(v[j].w);
    *reinterpret_cast<ushort4*>(dst + base + j * 1024) = b4;
  }
}

// -------- Front: router (atomic-free) + batched-ILP w1/w3[/w2] convs ------------
__global__ __launch_bounds__(256) void front_kernel(
    const float* __restrict__ x, const float* __restrict__ gw,
    const float* __restrict__ w1, const float* __restrict__ w3,
    const float* __restrict__ w2,
    float* __restrict__ out_logits, float* __restrict__ final_out,
    unsigned short* __restrict__ xbf,
    unsigned short* __restrict__ w1bf, unsigned short* __restrict__ w3bf,
    unsigned short* __restrict__ w2bf,
    int* __restrict__ sel01, float2* __restrict__ w01)
{
  int tid = threadIdx.x;
  int b = blockIdx.x;
  if (b >= TT) {
    int cb = b - TT;
    if (cb < NC32)          conv_ilp(w1, w1bf, cb, tid);
    else if (cb < 2 * NC32) conv_ilp(w3, w3bf, cb - NC32, tid);
    else                    conv_ilp(w2, w2bf, cb - 2 * NC32, tid);
    return;
  }
  int t = b;

  __shared__ float xs[HH];
  __shared__ float lg[EE];

  float4 v = reinterpret_cast<const float4*>(x + (size_t)t * HH)[tid];
  xs[tid * 4 + 0] = v.x; xs[tid * 4 + 1] = v.y;
  xs[tid * 4 + 2] = v.z; xs[tid * 4 + 3] = v.w;
  ushort4 b4;
  b4.x = f2b(v.x); b4.y = f2b(v.y); b4.z = f2b(v.z); b4.w = f2b(v.w);
  reinterpret_cast<ushort4*>(xbf + (size_t)t * HH)[tid] = b4;
  float4 z4; z4.x = z4.y = z4.z = z4.w = 0.f;
  reinterpret_cast<float4*>(final_out + (size_t)t * HH)[tid] = z4;
  __syncthreads();

  int lane = tid & 63, wv = tid >> 6;
  for (int e = wv; e < EE; e += 4) {
    float s = 0.f;
    const float* g = gw + (size_t)e * HH;
#pragma unroll
    for (int j = 0; j < HH / 64; ++j) s += xs[lane + j * 64] * g[lane + j * 64];
#pragma unroll
    for (int off = 32; off > 0; off >>= 1) s += __shfl_down(s, off);
    if (lane == 0) lg[e] = s;
  }
  __syncthreads();

  if (tid < 8) out_logits[(size_t)t * EE + tid] = lg[tid];
  if (tid == 0) {
    float l[EE];
#pragma unroll
    for (int e = 0; e < EE; ++e) l[e] = lg[e];
    int e0 = 0;
#pragma unroll
    for (int e = 1; e < EE; ++e) if (l[e] > l[e0]) e0 = e;
    int e1 = -1;
#pragma unroll
    for (int e = 0; e < EE; ++e) if (e != e0 && (e1 < 0 || l[e] > l[e1])) e1 = e;
    float p1 = expf(l[e1] - l[e0]);
    float w0 = 1.f / (1.f + p1);
    float w1v = p1 * w0;
    sel01[t] = e0 | (e1 << 8);
    w01[t] = make_float2(w0, w1v);
  }
}

// -------- Build: per-expert compacted token lists, atomic-free, deterministic ----
__global__ __launch_bounds__(256) void build_kernel(
    const int* __restrict__ sel01, const float2* __restrict__ w01,
    int* __restrict__ counts, int* __restrict__ tokidx, float* __restrict__ rww)
{
  int e = blockIdx.x;
  int tid = threadIdx.x, lane = tid & 63, wv = tid >> 6;
  __shared__ int wsum[4];
  int base = 0;
  for (int t0 = 0; t0 < TT; t0 += 256) {
    int t = t0 + tid;
    int s = sel01[t];
    int e0 = s & 255, e1 = (s >> 8) & 255;
    bool hit = (e0 == e) || (e1 == e);
    float w = 0.f;
    if (hit) { float2 ww = w01[t]; w = (e0 == e) ? ww.x : ww.y; }
    unsigned long long m = __ballot(hit);
    int wpre = __popcll(m & ((1ull << lane) - 1));
    if (lane == 63) wsum[wv] = wpre + (hit ? 1 : 0);
    __syncthreads();
    int wbase = base;
    for (int q = 0; q < wv; ++q) wbase += wsum[q];
    if (hit) {
      int pos = wbase + wpre;
      tokidx[e * TT + pos] = t;
      rww[e * TT + pos] = w;
    }
    base += wsum[0] + wsum[1] + wsum[2] + wsum[3];
    __syncthreads();
  }
  if (tid == 0) counts[e] = base;
}

// -------- Standalone conv for w2 (fallback when ws too small: after up_gate) ----
__global__ __launch_bounds__(256) void conv_kernel(
    const float* __restrict__ src, unsigned short* __restrict__ dst)
{
  conv_ilp(src, dst, blockIdx.x, threadIdx.x);
}

// -------- Up-proj + gate: R3-proven 2-phase dbuf, tile 128 x (64F x 2) ----------
__global__ __launch_bounds__(256) void up_gate_kernel(
    const unsigned short* __restrict__ xbf,
    const unsigned short* __restrict__ w1bf, const unsigned short* __restrict__ w3bf,
    const int* __restrict__ counts, const int* __restrict__ tokidx,
    unsigned short* __restrict__ gated)
{
  int e = blockIdx.z;
  int n = counts[e];
  int row0 = blockIdx.y * 128;
  if (row0 >= n) return;
  int fbase = blockIdx.x * 64;

  int pe = 0;
  for (int q = 0; q < e; ++q) pe += (counts[q] + 127) & ~127;

  __shared__ unsigned short As[2][128 * 32];   // 2 x 8 KB
  __shared__ unsigned short B1s[2][64 * 32];   // 2 x 4 KB
  __shared__ unsigned short B3s[2][64 * 32];   // 2 x 4 KB

  int tid = threadIdx.x;
  int lane = tid & 63, wv = tid >> 6;
  int srow = wv * 16 + (lane >> 2);      // 0..63
  int skoff = (lane & 3) * 8;            // k-offset (elements)

  int r0 = min(row0 + srow, n - 1);
  int r1 = min(row0 + 64 + srow, n - 1);
  int t0 = tokidx[e * TT + r0];
  int t1 = tokidx[e * TT + r1];
  const unsigned short* ga0 = xbf + (size_t)t0 * HH + skoff;
  const unsigned short* ga1 = xbf + (size_t)t1 * HH + skoff;
  const unsigned short* gb1 = w1bf + ((size_t)e * FF + fbase + srow) * HH + skoff;
  const unsigned short* gb3 = w3bf + ((size_t)e * FF + fbase + srow) * HH + skoff;

  int wr = (wv >> 1) * 64, wc = (wv & 1) * 32;
  int fr = lane & 15, fk = (lane >> 4) * 8;

  f32x4 acc1[4][2], acc3[4][2];
#pragma unroll
  for (int m = 0; m < 4; ++m)
#pragma unroll
    for (int nn = 0; nn < 2; ++nn) { acc1[m][nn] = (f32x4)0.f; acc3[m][nn] = (f32x4)0.f; }

  // prologue: stage tile 0 into buf 0
  gload16(ga0, &As[0][wv * 512]);
  gload16(ga1, &As[0][2048 + wv * 512]);
  gload16(gb1, &B1s[0][wv * 512]);
  gload16(gb3, &B3s[0][wv * 512]);

  int cur = 0;
  for (int k0 = 0; k0 < HH; k0 += 32) {
    __syncthreads();  // implicit vmcnt(0)+lgkmcnt(0): buf[cur] staged, prior reads drained
    if (k0 + 32 < HH) {
      int nxt = cur ^ 1, kn = k0 + 32;
      gload16(ga0 + kn, &As[nxt][wv * 512]);
      gload16(ga1 + kn, &As[nxt][2048 + wv * 512]);
      gload16(gb1 + kn, &B1s[nxt][wv * 512]);
      gload16(gb3 + kn, &B3s[nxt][wv * 512]);
    }

    short8_t a[4], b1f[2], b3f[2];
#pragma unroll
    for (int m = 0; m < 4; ++m)
      a[m] = *reinterpret_cast<const short8_t*>(&As[cur][(wr + m * 16 + fr) * 32 + fk]);
#pragma unroll
    for (int nn = 0; nn < 2; ++nn) {
      b1f[nn] = *reinterpret_cast<const short8_t*>(&B1s[cur][(wc + nn * 16 + fr) * 32 + fk]);
      b3f[nn] = *reinterpret_cast<const short8_t*>(&B3s[cur][(wc + nn * 16 + fr) * 32 + fk]);
    }
#pragma unroll
    for (int m = 0; m < 4; ++m)
#pragma unroll
      for (int nn = 0; nn < 2; ++nn) {
        acc1[m][nn] = __builtin_amdgcn_mfma_f32_16x16x32_bf16(a[m], b1f[nn], acc1[m][nn], 0, 0, 0);
        acc3[m][nn] = __builtin_amdgcn_mfma_f32_16x16x32_bf16(a[m], b3f[nn], acc3[m][nn], 0, 0, 0);
      }
    cur ^= 1;
  }

  // epilogue: gated = silu(h1)*h3 -> bf16
  size_t gbase = ((size_t)pe + row0) * FF + fbase;
#pragma unroll
  for (int m = 0; m < 4; ++m) {
#pragma unroll
    for (int nn = 0; nn < 2; ++nn) {
      f32x4 h1v = acc1[m][nn], h3v = acc3[m][nn];
#pragma unroll
      for (int j = 0; j < 4; ++j) {
        float z = h1v[j];
        float val = (z / (1.f + expf(-z))) * h3v[j];
        int r = wr + m * 16 + (lane >> 4) * 4 + j;
        int c = wc + nn * 16 + fr;
        gated[gbase + (size_t)r * FF + c] = f2b(val);
      }
    }
  }
}

// -------- Down-proj + weighted scatter: R3-proven 2-phase dbuf, tile 128 x 128 --
__global__ __launch_bounds__(256) void down_kernel(
    const unsigned short* __restrict__ gated,
    const unsigned short* __restrict__ w2bf,
    const int* __restrict__ counts, const int* __restrict__ tokidx,
    const float* __restrict__ rww,
    float* __restrict__ final_out)
{
  int e = blockIdx.z;
  int n = counts[e];
  int row0 = blockIdx.y * 128;
  if (row0 >= n) return;
  int hbase = blockIdx.x * 128;
  int valid = min(128, n - row0);

  int pe = 0;
  for (int q = 0; q < e; ++q) pe += (counts[q] + 127) & ~127;

  __shared__ unsigned short As[2][128 * 32];   // 2 x 8 KB
  __shared__ unsigned short Bs[2][128 * 32];   // 2 x 8 KB

  int tid = threadIdx.x;
  int lane = tid & 63, wv = tid >> 6;
  int srow = wv * 16 + (lane >> 2);
  int skoff = (lane & 3) * 8;

  const unsigned short* ga0 = gated + ((size_t)pe + row0 + srow) * FF + skoff;
  const unsigned short* ga1 = ga0 + (size_t)64 * FF;
  const unsigned short* gb0 = w2bf + ((size_t)e * HH + hbase + srow) * FF + skoff;
  const unsigned short* gb1 = gb0 + (size_t)64 * FF;

  int wr = (wv >> 1) * 64, wc = (wv & 1) * 64;
  int fr = lane & 15, fk = (lane >> 4) * 8;

  f32x4 acc[4][4];
#pragma unroll
  for (int m = 0; m < 4; ++m)
#pragma unroll
    for (int nn = 0; nn < 4; ++nn) acc[m][nn] = (f32x4)0.f;

  // prologue: stage tile 0 into buf 0
  gload16(ga0, &As[0][wv * 512]);
  gload16(ga1, &As[0][2048 + wv * 512]);
  gload16(gb0, &Bs[0][wv * 512]);
  gload16(gb1, &Bs[0][2048 + wv * 512]);

  int cur = 0;
  for (int k0 = 0; k0 < FF; k0 += 32) {
    __syncthreads();  // implicit vmcnt(0)+lgkmcnt(0)
    if (k0 + 32 < FF) {
      int nxt = cur ^ 1, kn = k0 + 32;
      gload16(ga0 + kn, &As[nxt][wv * 512]);
      gload16(ga1 + kn, &As[nxt][2048 + wv * 512]);
      gload16(gb0 + kn, &Bs[nxt][wv * 512]);
      gload16(gb1 + kn, &Bs[nxt][2048 + wv * 512]);
    }

    short8_t a[4], bf[4];
#pragma unroll
    for (int m = 0; m < 4; ++m)
      a[m] = *reinterpret_cast<const short8_t*>(&As[cur][(wr + m * 16 + fr) * 32 + fk]);
#pragma unroll
    for (int nn = 0; nn < 4; ++nn)
      bf[nn] = *reinterpret_cast<const short8_t*>(&Bs[cur][(wc + nn * 16 + fr) * 32 + fk]);
#pragma unroll
    for (int m = 0; m < 4; ++m)
#pragma unroll
      for (int nn = 0; nn < 4; ++nn)
        acc[m][nn] = __builtin_amdgcn_mfma_f32_16x16x32_bf16(a[m], bf[nn], acc[m][nn], 0, 0, 0);
    cur ^= 1;
  }

  // epilogue: final[t, h] += rw * out  (2 commutative f32 adds per element)
#pragma unroll
  for (int m = 0; m < 4; ++m) {
    int rbase = wr + m * 16 + (lane >> 4) * 4;
#pragma unroll
    for (int j = 0; j < 4; ++j) {
      int r = rbase + j;
      if (r < valid) {
        int t = tokidx[e * TT + row0 + r];
        float w = rww[e * TT + row0 + r];
#pragma unroll
        for (int nn = 0; nn < 4; ++nn) {
          int c = hbase + wc + nn * 16 + fr;
          atomicAdd(&final_out[(size_t)t * HH + c], w * acc[m][nn][j]);
        }
      }
    }
  }
}

extern "C" void kernel_launch(void* const* d_in, const int* in_sizes, int n_in,
                              void* d_out, int out_size, void* d_ws, size_t ws_size,
                              hipStream_t stream) {
  const float* x  = (const float*)d_in[0];   // [T, H]
  const float* gw = (const float*)d_in[1];   // [E, H]
  const float* w1 = (const float*)d_in[2];   // [E, F, H]
  const float* w2 = (const float*)d_in[3];   // [E, H, F]
  const float* w3 = (const float*)d_in[4];   // [E, F, H]

  float* final_out  = (float*)d_out;                       // [T, H]
  float* out_logits = final_out + (size_t)TT * HH;         // [T, E]

  char* ws = (char*)d_ws;
  int*    counts = (int*)(ws + 0);                            // 64 B
  int*    sel01  = (int*)(ws + 1024);                         // 16384
  float2* w01    = (float2*)(ws + 20480);                     // 32768
  int*    tokidx = (int*)(ws + 53248);                        // 131072
  float*  rww    = (float*)(ws + 184320);                     // 131072
  unsigned short* xbf   = (unsigned short*)(ws + 315392);     // 8388608
  unsigned short* w1bf  = (unsigned short*)(ws + 8704000);    // 33554432
  unsigned short* w3bf  = (unsigned short*)(ws + 42258432);   // 33554432
  unsigned short* gated = (unsigned short*)(ws + 75812864);   // 37748736
  const size_t base_end = 113561600;
  bool big = ws_size >= base_end + 33554432;                  // +32MB for w2bf
  unsigned short* w2bf = big ? (unsigned short*)(ws + base_end) : w1bf;

  int nconvblk = (big ? 3 : 2) * NC32;
  front_kernel<<<TT + nconvblk, 256, 0, stream>>>(
      x, gw, w1, w3, w2, out_logits, final_out, xbf, w1bf, w3bf, w2bf,
      sel01, w01);
  build_kernel<<<EE, 256, 0, stream>>>(sel01, w01, counts, tokidx, rww);
  up_gate_kernel<<<dim3(FF / 64, TT / 128, EE), 256, 0, stream>>>(
      xbf, w1bf, w3bf, counts, tokidx, gated);
  if (!big) conv_kernel<<<NC32, 256, 0, stream>>>(w2, w1bf);
  down_kernel<<<dim3(HH / 128, TT / 128, EE), 256, 0, stream>>>(
      gated, w2bf, counts, tokidx, rww, final_out);
}

// Round 8
// 258.612 us; speedup vs baseline: 1.2159x; 1.0292x over previous
//
#include <hip/hip_runtime.h>
#include <hip/hip_bf16.h>

// MoE: B=2,S=2048 -> T=4096 tokens, H=1024, F=2048, E=8, TOPK=2
#define TT 4096
#define HH 1024
#define FF 2048
#define EE 8
#define NC32 2048   // EE*FF*HH / (256*32) conv chunks per weight tensor
#define LDSU 32768  // LDS slot stride (bytes)

typedef short short8_t __attribute__((ext_vector_type(8)));
typedef float f32x4 __attribute__((ext_vector_type(4)));

__device__ __forceinline__ unsigned short f2b(float f) {
  union { float f; unsigned u; } v; v.f = f;
  return (unsigned short)((v.u + 0x7fffu + ((v.u >> 16) & 1u)) >> 16);  // RNE
}

__device__ __forceinline__ void gload16(const unsigned short* g, void* l) {
  __builtin_amdgcn_global_load_lds(
      (const __attribute__((address_space(1))) void*)g,
      (__attribute__((address_space(3))) void*)l, 16, 0, 0);
}

#define FENCE asm volatile("" ::: "memory")

// Batched-ILP f32->bf16 conv: 8 independent float4 loads in flight per thread.
__device__ __forceinline__ void conv_ilp(const float* __restrict__ src,
                                         unsigned short* __restrict__ dst,
                                         int c, int tid) {
  size_t base = (size_t)c * 8192 + tid * 4;
  float4 v[8];
#pragma unroll
  for (int j = 0; j < 8; ++j)
    v[j] = *reinterpret_cast<const float4*>(src + base + j * 1024);
#pragma unroll
  for (int j = 0; j < 8; ++j) {
    ushort4 b4;
    b4.x = f2b(v[j].x); b4.y = f2b(v[j].y); b4.z = f2b(v[j].z); b4.w = f2b(v[j].w);
    *reinterpret_cast<ushort4*>(dst + base + j * 1024) = b4;
  }
}

// -------- Front: router (atomic-free) + batched-ILP w1/w3[/w2] convs ------------
__global__ __launch_bounds__(256) void front_kernel(
    const float* __restrict__ x, const float* __restrict__ gw,
    const float* __restrict__ w1, const float* __restrict__ w3,
    const float* __restrict__ w2,
    float* __restrict__ out_logits, float* __restrict__ final_out,
    unsigned short* __restrict__ xbf,
    unsigned short* __restrict__ w1bf, unsigned short* __restrict__ w3bf,
    unsigned short* __restrict__ w2bf,
    int* __restrict__ sel01, float2* __restrict__ w01)
{
  int tid = threadIdx.x;
  int b = blockIdx.x;
  if (b >= TT) {
    int cb = b - TT;
    if (cb < NC32)          conv_ilp(w1, w1bf, cb, tid);
    else if (cb < 2 * NC32) conv_ilp(w3, w3bf, cb - NC32, tid);
    else                    conv_ilp(w2, w2bf, cb - 2 * NC32, tid);
    return;
  }
  int t = b;

  __shared__ float xs[HH];
  __shared__ float lg[EE];

  float4 v = reinterpret_cast<const float4*>(x + (size_t)t * HH)[tid];
  xs[tid * 4 + 0] = v.x; xs[tid * 4 + 1] = v.y;
  xs[tid * 4 + 2] = v.z; xs[tid * 4 + 3] = v.w;
  ushort4 b4;
  b4.x = f2b(v.x); b4.y = f2b(v.y); b4.z = f2b(v.z); b4.w = f2b(v.w);
  reinterpret_cast<ushort4*>(xbf + (size_t)t * HH)[tid] = b4;
  float4 z4; z4.x = z4.y = z4.z = z4.w = 0.f;
  reinterpret_cast<float4*>(final_out + (size_t)t * HH)[tid] = z4;
  __syncthreads();

  int lane = tid & 63, wv = tid >> 6;
  for (int e = wv; e < EE; e += 4) {
    float s = 0.f;
    const float* g = gw + (size_t)e * HH;
#pragma unroll
    for (int j = 0; j < HH / 64; ++j) s += xs[lane + j * 64] * g[lane + j * 64];
#pragma unroll
    for (int off = 32; off > 0; off >>= 1) s += __shfl_down(s, off);
    if (lane == 0) lg[e] = s;
  }
  __syncthreads();

  if (tid < 8) out_logits[(size_t)t * EE + tid] = lg[tid];
  if (tid == 0) {
    float l[EE];
#pragma unroll
    for (int e = 0; e < EE; ++e) l[e] = lg[e];
    int e0 = 0;
#pragma unroll
    for (int e = 1; e < EE; ++e) if (l[e] > l[e0]) e0 = e;
    int e1 = -1;
#pragma unroll
    for (int e = 0; e < EE; ++e) if (e != e0 && (e1 < 0 || l[e] > l[e1])) e1 = e;
    float p1 = expf(l[e1] - l[e0]);
    float w0 = 1.f / (1.f + p1);
    float w1v = p1 * w0;
    sel01[t] = e0 | (e1 << 8);
    w01[t] = make_float2(w0, w1v);
  }
}

// -------- Build: per-expert compacted token lists, atomic-free, deterministic ----
__global__ __launch_bounds__(256) void build_kernel(
    const int* __restrict__ sel01, const float2* __restrict__ w01,
    int* __restrict__ counts, int* __restrict__ tokidx, float* __restrict__ rww)
{
  int e = blockIdx.x;
  int tid = threadIdx.x, lane = tid & 63, wv = tid >> 6;
  __shared__ int wsum[4];
  int base = 0;
  for (int t0 = 0; t0 < TT; t0 += 256) {
    int t = t0 + tid;
    int s = sel01[t];
    int e0 = s & 255, e1 = (s >> 8) & 255;
    bool hit = (e0 == e) || (e1 == e);
    float w = 0.f;
    if (hit) { float2 ww = w01[t]; w = (e0 == e) ? ww.x : ww.y; }
    unsigned long long m = __ballot(hit);
    int wpre = __popcll(m & ((1ull << lane) - 1));
    if (lane == 63) wsum[wv] = wpre + (hit ? 1 : 0);
    __syncthreads();
    int wbase = base;
    for (int q = 0; q < wv; ++q) wbase += wsum[q];
    if (hit) {
      int pos = wbase + wpre;
      tokidx[e * TT + pos] = t;
      rww[e * TT + pos] = w;
    }
    base += wsum[0] + wsum[1] + wsum[2] + wsum[3];
    __syncthreads();
  }
  if (tid == 0) counts[e] = base;
}

// -------- Standalone conv for w2 (fallback when ws too small: after up_gate) ----
__global__ __launch_bounds__(256) void conv_kernel(
    const float* __restrict__ src, unsigned short* __restrict__ dst)
{
  conv_ilp(src, dst, blockIdx.x, threadIdx.x);
}

// -------- Up-proj + gate: BK=64, 2-slot counted-vmcnt pipeline, XOR-swizzle -----
// Slot layout (bytes): A[0,16384) 128x64, B1[16384,24576) 64x64, B3[24576,32768).
// Swizzle: 16B-block index ^= (row & 7); applied on global SOURCE at stage time
// (LDS dest stays linear, per global_load_lds semantics) and on ds_read address.
__global__ __launch_bounds__(256) void up_gate_kernel(
    const unsigned short* __restrict__ xbf,
    const unsigned short* __restrict__ w1bf, const unsigned short* __restrict__ w3bf,
    const int* __restrict__ counts, const int* __restrict__ tokidx,
    unsigned short* __restrict__ gated)
{
  int e = blockIdx.z;
  int n = counts[e];
  int row0 = blockIdx.y * 128;
  if (row0 >= n) return;
  int fbase = blockIdx.x * 64;

  int pe = 0;
  for (int q = 0; q < e; ++q) pe += (counts[q] + 127) & ~127;

  __shared__ __align__(16) char lds[2 * LDSU];   // 64 KB

  int tid = threadIdx.x;
  int lane = tid & 63, wv = tid >> 6;
  int sb = (tid & 7) ^ ((tid >> 3) & 7);   // swizzled source 16B-block (row&7 == (tid>>3)&7)

  // source pointers (per-thread; A rows gathered via token list, clamped)
  const unsigned short* ga[4];
#pragma unroll
  for (int j = 0; j < 4; ++j) {
    int r = min(row0 + (tid >> 3) + 32 * j, n - 1);
    ga[j] = xbf + (size_t)tokidx[e * TT + r] * HH + sb * 8;
  }
  const unsigned short* gb1[2];
  const unsigned short* gb3[2];
#pragma unroll
  for (int j = 0; j < 2; ++j) {
    size_t rw_ = (size_t)e * FF + fbase + (tid >> 3) + 32 * j;
    gb1[j] = w1bf + rw_ * HH + sb * 8;
    gb3[j] = w3bf + rw_ * HH + sb * 8;
  }

  int wr = (wv >> 1) * 64, wc = (wv & 1) * 32;
  int fr = lane & 15, kq = lane >> 4, l7 = lane & 7;

  f32x4 acc1[4][2], acc3[4][2];
#pragma unroll
  for (int m = 0; m < 4; ++m)
#pragma unroll
    for (int nn = 0; nn < 2; ++nn) { acc1[m][nn] = (f32x4)0.f; acc3[m][nn] = (f32x4)0.f; }

#define UG_STAGE(T, SOFF) do {                                                     \
    _Pragma("unroll") for (int j = 0; j < 4; ++j)                                  \
      gload16(ga[j] + (T) * 64, lds + (SOFF) + j * 4096 + wv * 1024);              \
    _Pragma("unroll") for (int j = 0; j < 2; ++j) {                                \
      gload16(gb1[j] + (T) * 64, lds + (SOFF) + 16384 + j * 4096 + wv * 1024);     \
      gload16(gb3[j] + (T) * 64, lds + (SOFF) + 24576 + j * 4096 + wv * 1024);     \
    } } while (0)

#define UG_COMPUTE(SOFF) do {                                                               \
    _Pragma("unroll") for (int ks = 0; ks < 2; ++ks) {                                      \
      int bswz = ((ks * 4 + kq) ^ l7) * 16;                                                 \
      short8_t a[4], b1f[2], b3f[2];                                                        \
      _Pragma("unroll") for (int m = 0; m < 4; ++m)                                         \
        a[m] = *(const short8_t*)(lds + (SOFF) + (wr + m * 16 + fr) * 128 + bswz);          \
      _Pragma("unroll") for (int nn = 0; nn < 2; ++nn) {                                    \
        b1f[nn] = *(const short8_t*)(lds + (SOFF) + 16384 + (wc + nn * 16 + fr) * 128 + bswz); \
        b3f[nn] = *(const short8_t*)(lds + (SOFF) + 24576 + (wc + nn * 16 + fr) * 128 + bswz); \
      }                                                                                     \
      _Pragma("unroll") for (int m = 0; m < 4; ++m)                                         \
        _Pragma("unroll") for (int nn = 0; nn < 2; ++nn) {                                  \
          acc1[m][nn] = __builtin_amdgcn_mfma_f32_16x16x32_bf16(a[m], b1f[nn], acc1[m][nn], 0, 0, 0); \
          acc3[m][nn] = __builtin_amdgcn_mfma_f32_16x16x32_bf16(a[m], b3f[nn], acc3[m][nn], 0, 0, 0); \
        } } } while (0)

#define UG_NT 16
#define UG_ITER(T, SOFF) do {                                          \
    if ((T) < UG_NT - 1) asm volatile("s_waitcnt vmcnt(8)" ::: "memory"); \
    else                 asm volatile("s_waitcnt vmcnt(0)" ::: "memory"); \
    __builtin_amdgcn_s_barrier(); FENCE;                               \
    UG_COMPUTE(SOFF);                                                  \
    FENCE; __builtin_amdgcn_s_barrier(); FENCE;                        \
    if ((T) + 2 < UG_NT) UG_STAGE((T) + 2, SOFF);                      \
  } while (0)

  UG_STAGE(0, 0);
  UG_STAGE(1, LDSU);
  for (int t2 = 0; t2 < UG_NT; t2 += 2) { UG_ITER(t2, 0); UG_ITER(t2 + 1, LDSU); }
#undef UG_STAGE
#undef UG_COMPUTE
#undef UG_ITER

  // epilogue: gated = silu(h1)*h3 -> bf16
  size_t gbase = ((size_t)pe + row0) * FF + fbase;
#pragma unroll
  for (int m = 0; m < 4; ++m) {
#pragma unroll
    for (int nn = 0; nn < 2; ++nn) {
      f32x4 h1v = acc1[m][nn], h3v = acc3[m][nn];
#pragma unroll
      for (int j = 0; j < 4; ++j) {
        float z = h1v[j];
        float val = (z / (1.f + expf(-z))) * h3v[j];
        int r = wr + m * 16 + (lane >> 4) * 4 + j;
        int c = wc + nn * 16 + fr;
        gated[gbase + (size_t)r * FF + c] = f2b(val);
      }
    }
  }
}

// -------- Down-proj + weighted scatter: BK=64, 2-slot counted-vmcnt, swizzle ----
// Slot layout (bytes): A[0,16384) 128x64, B[16384,32768) 128x64.
__global__ __launch_bounds__(256) void down_kernel(
    const unsigned short* __restrict__ gated,
    const unsigned short* __restrict__ w2bf,
    const int* __restrict__ counts, const int* __restrict__ tokidx,
    const float* __restrict__ rww,
    float* __restrict__ final_out)
{
  int e = blockIdx.z;
  int n = counts[e];
  int row0 = blockIdx.y * 128;
  if (row0 >= n) return;
  int hbase = blockIdx.x * 128;
  int valid = min(128, n - row0);

  int pe = 0;
  for (int q = 0; q < e; ++q) pe += (counts[q] + 127) & ~127;

  __shared__ __align__(16) char lds[2 * LDSU];   // 64 KB

  int tid = threadIdx.x;
  int lane = tid & 63, wv = tid >> 6;
  int sb = (tid & 7) ^ ((tid >> 3) & 7);

  const unsigned short* ga[4];
  const unsigned short* gb[4];
#pragma unroll
  for (int j = 0; j < 4; ++j) {
    ga[j] = gated + ((size_t)pe + row0 + (tid >> 3) + 32 * j) * FF + sb * 8;
    gb[j] = w2bf + ((size_t)e * HH + hbase + (tid >> 3) + 32 * j) * FF + sb * 8;
  }

  int wr = (wv >> 1) * 64, wc = (wv & 1) * 64;
  int fr = lane & 15, kq = lane >> 4, l7 = lane & 7;

  f32x4 acc[4][4];
#pragma unroll
  for (int m = 0; m < 4; ++m)
#pragma unroll
    for (int nn = 0; nn < 4; ++nn) acc[m][nn] = (f32x4)0.f;

#define DN_STAGE(T, SOFF) do {                                                   \
    _Pragma("unroll") for (int j = 0; j < 4; ++j) {                              \
      gload16(ga[j] + (T) * 64, lds + (SOFF) + j * 4096 + wv * 1024);            \
      gload16(gb[j] + (T) * 64, lds + (SOFF) + 16384 + j * 4096 + wv * 1024);    \
    } } while (0)

#define DN_COMPUTE(SOFF) do {                                                              \
    _Pragma("unroll") for (int ks = 0; ks < 2; ++ks) {                                     \
      int bswz = ((ks * 4 + kq) ^ l7) * 16;                                                \
      short8_t a[4], bf[4];                                                                \
      _Pragma("unroll") for (int m = 0; m < 4; ++m)                                        \
        a[m] = *(const short8_t*)(lds + (SOFF) + (wr + m * 16 + fr) * 128 + bswz);         \
      _Pragma("unroll") for (int nn = 0; nn < 4; ++nn)                                     \
        bf[nn] = *(const short8_t*)(lds + (SOFF) + 16384 + (wc + nn * 16 + fr) * 128 + bswz); \
      _Pragma("unroll") for (int m = 0; m < 4; ++m)                                        \
        _Pragma("unroll") for (int nn = 0; nn < 4; ++nn)                                   \
          acc[m][nn] = __builtin_amdgcn_mfma_f32_16x16x32_bf16(a[m], bf[nn], acc[m][nn], 0, 0, 0); \
    } } while (0)

#define DN_NT 32
#define DN_ITER(T, SOFF) do {                                          \
    if ((T) < DN_NT - 1) asm volatile("s_waitcnt vmcnt(8)" ::: "memory"); \
    else                 asm volatile("s_waitcnt vmcnt(0)" ::: "memory"); \
    __builtin_amdgcn_s_barrier(); FENCE;                               \
    DN_COMPUTE(SOFF);                                                  \
    FENCE; __builtin_amdgcn_s_barrier(); FENCE;                        \
    if ((T) + 2 < DN_NT) DN_STAGE((T) + 2, SOFF);                      \
  } while (0)

  DN_STAGE(0, 0);
  DN_STAGE(1, LDSU);
  for (int t2 = 0; t2 < DN_NT; t2 += 2) { DN_ITER(t2, 0); DN_ITER(t2 + 1, LDSU); }
#undef DN_STAGE
#undef DN_COMPUTE
#undef DN_ITER

  // epilogue: final[t, h] += rw * out  (2 commutative f32 adds per element)
#pragma unroll
  for (int m = 0; m < 4; ++m) {
    int rbase = wr + m * 16 + (lane >> 4) * 4;
#pragma unroll
    for (int j = 0; j < 4; ++j) {
      int r = rbase + j;
      if (r < valid) {
        int t = tokidx[e * TT + row0 + r];
        float w = rww[e * TT + row0 + r];
#pragma unroll
        for (int nn = 0; nn < 4; ++nn) {
          int c = hbase + wc + nn * 16 + fr;
          atomicAdd(&final_out[(size_t)t * HH + c], w * acc[m][nn][j]);
        }
      }
    }
  }
}

extern "C" void kernel_launch(void* const* d_in, const int* in_sizes, int n_in,
                              void* d_out, int out_size, void* d_ws, size_t ws_size,
                              hipStream_t stream) {
  const float* x  = (const float*)d_in[0];   // [T, H]
  const float* gw = (const float*)d_in[1];   // [E, H]
  const float* w1 = (const float*)d_in[2];   // [E, F, H]
  const float* w2 = (const float*)d_in[3];   // [E, H, F]
  const float* w3 = (const float*)d_in[4];   // [E, F, H]

  float* final_out  = (float*)d_out;                       // [T, H]
  float* out_logits = final_out + (size_t)TT * HH;         // [T, E]

  char* ws = (char*)d_ws;
  int*    counts = (int*)(ws + 0);                            // 64 B
  int*    sel01  = (int*)(ws + 1024);                         // 16384
  float2* w01    = (float2*)(ws + 20480);                     // 32768
  int*    tokidx = (int*)(ws + 53248);                        // 131072
  float*  rww    = (float*)(ws + 184320);                     // 131072
  unsigned short* xbf   = (unsigned short*)(ws + 315392);     // 8388608
  unsigned short* w1bf  = (unsigned short*)(ws + 8704000);    // 33554432
  unsigned short* w3bf  = (unsigned short*)(ws + 42258432);   // 33554432
  unsigned short* gated = (unsigned short*)(ws + 75812864);   // 37748736
  const size_t base_end = 113561600;
  bool big = ws_size >= base_end + 33554432;                  // +32MB for w2bf
  unsigned short* w2bf = big ? (unsigned short*)(ws + base_end) : w1bf;

  int nconvblk = (big ? 3 : 2) * NC32;
  front_kernel<<<TT + nconvblk, 256, 0, stream>>>(
      x, gw, w1, w3, w2, out_logits, final_out, xbf, w1bf, w3bf, w2bf,
      sel01, w01);
  build_kernel<<<EE, 256, 0, stream>>>(sel01, w01, counts, tokidx, rww);
  up_gate_kernel<<<dim3(FF / 64, TT / 128, EE), 256, 0, stream>>>(
      xbf, w1bf, w3bf, counts, tokidx, gated);
  if (!big) conv_kernel<<<NC32, 256, 0, stream>>>(w2, w1bf);
  down_kernel<<<dim3(HH / 128, TT / 128, EE), 256, 0, stream>>>(
      gated, w2bf, counts, tokidx, rww, final_out);
}

// Round 9
// 253.778 us; speedup vs baseline: 1.2390x; 1.0190x over previous
//
#include <hip/hip_runtime.h>
#include <hip/hip_bf16.h>

// MoE: B=2,S=2048 -> T=4096 tokens, H=1024, F=2048, E=8, TOPK=2
#define TT 4096
#define HH 1024
#define FF 2048
#define EE 8
#define NC32 2048   // EE*FF*HH / (256*32) conv chunks per weight tensor
#define LDSU 32768  // LDS slot stride (bytes)

typedef short short8_t __attribute__((ext_vector_type(8)));
typedef float f32x4 __attribute__((ext_vector_type(4)));

__device__ __forceinline__ unsigned short f2b(float f) {
  union { float f; unsigned u; } v; v.f = f;
  return (unsigned short)((v.u + 0x7fffu + ((v.u >> 16) & 1u)) >> 16);  // RNE
}

__device__ __forceinline__ void gload16(const unsigned short* g, void* l) {
  __builtin_amdgcn_global_load_lds(
      (const __attribute__((address_space(1))) void*)g,
      (__attribute__((address_space(3))) void*)l, 16, 0, 0);
}

#define FENCE asm volatile("" ::: "memory")

// Batched-ILP f32->bf16 conv: 8 independent float4 loads in flight per thread.
__device__ __forceinline__ void conv_ilp(const float* __restrict__ src,
                                         unsigned short* __restrict__ dst,
                                         int c, int tid) {
  size_t base = (size_t)c * 8192 + tid * 4;
  float4 v[8];
#pragma unroll
  for (int j = 0; j < 8; ++j)
    v[j] = *reinterpret_cast<const float4*>(src + base + j * 1024);
#pragma unroll
  for (int j = 0; j < 8; ++j) {
    ushort4 b4;
    b4.x = f2b(v[j].x); b4.y = f2b(v[j].y); b4.z = f2b(v[j].z); b4.w = f2b(v[j].w);
    *reinterpret_cast<ushort4*>(dst + base + j * 1024) = b4;
  }
}

// -------- Front: router (atomic-free) + batched-ILP w1/w3[/w2] convs ------------
__global__ __launch_bounds__(256) void front_kernel(
    const float* __restrict__ x, const float* __restrict__ gw,
    const float* __restrict__ w1, const float* __restrict__ w3,
    const float* __restrict__ w2,
    float* __restrict__ out_logits, float* __restrict__ final_out,
    unsigned short* __restrict__ xbf,
    unsigned short* __restrict__ w1bf, unsigned short* __restrict__ w3bf,
    unsigned short* __restrict__ w2bf,
    int* __restrict__ sel01, float2* __restrict__ w01)
{
  int tid = threadIdx.x;
  int b = blockIdx.x;
  if (b >= TT) {
    int cb = b - TT;
    if (cb < NC32)          conv_ilp(w1, w1bf, cb, tid);
    else if (cb < 2 * NC32) conv_ilp(w3, w3bf, cb - NC32, tid);
    else                    conv_ilp(w2, w2bf, cb - 2 * NC32, tid);
    return;
  }
  int t = b;

  __shared__ float xs[HH];
  __shared__ float lg[EE];

  float4 v = reinterpret_cast<const float4*>(x + (size_t)t * HH)[tid];
  xs[tid * 4 + 0] = v.x; xs[tid * 4 + 1] = v.y;
  xs[tid * 4 + 2] = v.z; xs[tid * 4 + 3] = v.w;
  ushort4 b4;
  b4.x = f2b(v.x); b4.y = f2b(v.y); b4.z = f2b(v.z); b4.w = f2b(v.w);
  reinterpret_cast<ushort4*>(xbf + (size_t)t * HH)[tid] = b4;
  float4 z4; z4.x = z4.y = z4.z = z4.w = 0.f;
  reinterpret_cast<float4*>(final_out + (size_t)t * HH)[tid] = z4;
  __syncthreads();

  int lane = tid & 63, wv = tid >> 6;
  for (int e = wv; e < EE; e += 4) {
    float s = 0.f;
    const float* g = gw + (size_t)e * HH;
#pragma unroll
    for (int j = 0; j < HH / 64; ++j) s += xs[lane + j * 64] * g[lane + j * 64];
#pragma unroll
    for (int off = 32; off > 0; off >>= 1) s += __shfl_down(s, off);
    if (lane == 0) lg[e] = s;
  }
  __syncthreads();

  if (tid < 8) out_logits[(size_t)t * EE + tid] = lg[tid];
  if (tid == 0) {
    float l[EE];
#pragma unroll
    for (int e = 0; e < EE; ++e) l[e] = lg[e];
    int e0 = 0;
#pragma unroll
    for (int e = 1; e < EE; ++e) if (l[e] > l[e0]) e0 = e;
    int e1 = -1;
#pragma unroll
    for (int e = 0; e < EE; ++e) if (e != e0 && (e1 < 0 || l[e] > l[e1])) e1 = e;
    float p1 = expf(l[e1] - l[e0]);
    float w0 = 1.f / (1.f + p1);
    float w1v = p1 * w0;
    sel01[t] = e0 | (e1 << 8);
    w01[t] = make_float2(w0, w1v);
  }
}

// -------- Build: per-expert compacted token lists, atomic-free, deterministic ----
__global__ __launch_bounds__(256) void build_kernel(
    const int* __restrict__ sel01, const float2* __restrict__ w01,
    int* __restrict__ counts, int* __restrict__ tokidx, float* __restrict__ rww)
{
  int e = blockIdx.x;
  int tid = threadIdx.x, lane = tid & 63, wv = tid >> 6;
  __shared__ int wsum[4];
  int base = 0;
  for (int t0 = 0; t0 < TT; t0 += 256) {
    int t = t0 + tid;
    int s = sel01[t];
    int e0 = s & 255, e1 = (s >> 8) & 255;
    bool hit = (e0 == e) || (e1 == e);
    float w = 0.f;
    if (hit) { float2 ww = w01[t]; w = (e0 == e) ? ww.x : ww.y; }
    unsigned long long m = __ballot(hit);
    int wpre = __popcll(m & ((1ull << lane) - 1));
    if (lane == 63) wsum[wv] = wpre + (hit ? 1 : 0);
    __syncthreads();
    int wbase = base;
    for (int q = 0; q < wv; ++q) wbase += wsum[q];
    if (hit) {
      int pos = wbase + wpre;
      tokidx[e * TT + pos] = t;
      rww[e * TT + pos] = w;
    }
    base += wsum[0] + wsum[1] + wsum[2] + wsum[3];
    __syncthreads();
  }
  if (tid == 0) counts[e] = base;
}

// -------- Standalone conv for w2 (fallback when ws too small: after up_gate) ----
__global__ __launch_bounds__(256) void conv_kernel(
    const float* __restrict__ src, unsigned short* __restrict__ dst)
{
  conv_ilp(src, dst, blockIdx.x, threadIdx.x);
}

// -------- Up-proj + gate: BK=64, 2-slot counted-vmcnt, 2 sub-phases + setprio ---
// Slot layout (bytes): A[0,16384) 128x64, B1[16384,24576) 64x64, B3[24576,32768).
// Swizzle: 16B-block index ^= (row & 7); pre-swizzled global SOURCE at stage time
// (LDS dest linear, per global_load_lds semantics) + swizzled ds_read address.
__global__ __launch_bounds__(256) void up_gate_kernel(
    const unsigned short* __restrict__ xbf,
    const unsigned short* __restrict__ w1bf, const unsigned short* __restrict__ w3bf,
    const int* __restrict__ counts, const int* __restrict__ tokidx,
    unsigned short* __restrict__ gated)
{
  int e = blockIdx.z;
  int n = counts[e];
  int row0 = blockIdx.y * 128;
  if (row0 >= n) return;
  int fbase = blockIdx.x * 64;

  int pe = 0;
  for (int q = 0; q < e; ++q) pe += (counts[q] + 127) & ~127;

  __shared__ __align__(16) char lds[2 * LDSU];   // 64 KB

  int tid = threadIdx.x;
  int lane = tid & 63, wv = tid >> 6;
  int sb = (tid & 7) ^ ((tid >> 3) & 7);   // swizzled source 16B-block (row&7 == (tid>>3)&7)

  const unsigned short* ga[4];
#pragma unroll
  for (int j = 0; j < 4; ++j) {
    int r = min(row0 + (tid >> 3) + 32 * j, n - 1);
    ga[j] = xbf + (size_t)tokidx[e * TT + r] * HH + sb * 8;
  }
  const unsigned short* gb1[2];
  const unsigned short* gb3[2];
#pragma unroll
  for (int j = 0; j < 2; ++j) {
    size_t rw_ = (size_t)e * FF + fbase + (tid >> 3) + 32 * j;
    gb1[j] = w1bf + rw_ * HH + sb * 8;
    gb3[j] = w3bf + rw_ * HH + sb * 8;
  }

  int wr = (wv >> 1) * 64, wc = (wv & 1) * 32;
  int fr = lane & 15, kq = lane >> 4, l7 = lane & 7;

  f32x4 acc1[4][2], acc3[4][2];
#pragma unroll
  for (int m = 0; m < 4; ++m)
#pragma unroll
    for (int nn = 0; nn < 2; ++nn) { acc1[m][nn] = (f32x4)0.f; acc3[m][nn] = (f32x4)0.f; }

#define UG_STAGE(T, SOFF) do {                                                     \
    _Pragma("unroll") for (int j = 0; j < 4; ++j)                                  \
      gload16(ga[j] + (T) * 64, lds + (SOFF) + j * 4096 + wv * 1024);              \
    _Pragma("unroll") for (int j = 0; j < 2; ++j) {                                \
      gload16(gb1[j] + (T) * 64, lds + (SOFF) + 16384 + j * 4096 + wv * 1024);     \
      gload16(gb3[j] + (T) * 64, lds + (SOFF) + 24576 + j * 4096 + wv * 1024);     \
    } } while (0)

#define UG_PHASE(SOFF, KS) do {                                                             \
    int bswz = (((KS) * 4 + kq) ^ l7) * 16;                                                 \
    short8_t a[4], b1f[2], b3f[2];                                                          \
    _Pragma("unroll") for (int m = 0; m < 4; ++m)                                           \
      a[m] = *(const short8_t*)(lds + (SOFF) + (wr + m * 16 + fr) * 128 + bswz);            \
    _Pragma("unroll") for (int nn = 0; nn < 2; ++nn) {                                      \
      b1f[nn] = *(const short8_t*)(lds + (SOFF) + 16384 + (wc + nn * 16 + fr) * 128 + bswz); \
      b3f[nn] = *(const short8_t*)(lds + (SOFF) + 24576 + (wc + nn * 16 + fr) * 128 + bswz); \
    }                                                                                       \
    __builtin_amdgcn_s_setprio(1);                                                          \
    _Pragma("unroll") for (int m = 0; m < 4; ++m)                                           \
      _Pragma("unroll") for (int nn = 0; nn < 2; ++nn) {                                    \
        acc1[m][nn] = __builtin_amdgcn_mfma_f32_16x16x32_bf16(a[m], b1f[nn], acc1[m][nn], 0, 0, 0); \
        acc3[m][nn] = __builtin_amdgcn_mfma_f32_16x16x32_bf16(a[m], b3f[nn], acc3[m][nn], 0, 0, 0); \
      }                                                                                     \
    __builtin_amdgcn_s_setprio(0);                                                          \
  } while (0)

#define UG_NT 16
#define UG_ITER(T, SOFF) do {                                          \
    if ((T) < UG_NT - 1) asm volatile("s_waitcnt vmcnt(8)" ::: "memory"); \
    else                 asm volatile("s_waitcnt vmcnt(0)" ::: "memory"); \
    __builtin_amdgcn_s_barrier(); FENCE;                               \
    UG_PHASE(SOFF, 0);                                                 \
    FENCE; __builtin_amdgcn_s_barrier(); FENCE;                        \
    UG_PHASE(SOFF, 1);                                                 \
    FENCE; __builtin_amdgcn_s_barrier(); FENCE;                        \
    if ((T) + 2 < UG_NT) UG_STAGE((T) + 2, SOFF);                      \
  } while (0)

  UG_STAGE(0, 0);
  UG_STAGE(1, LDSU);
  for (int t2 = 0; t2 < UG_NT; t2 += 2) { UG_ITER(t2, 0); UG_ITER(t2 + 1, LDSU); }
#undef UG_STAGE
#undef UG_PHASE
#undef UG_ITER

  // epilogue: gated = silu(h1)*h3 -> bf16
  size_t gbase = ((size_t)pe + row0) * FF + fbase;
#pragma unroll
  for (int m = 0; m < 4; ++m) {
#pragma unroll
    for (int nn = 0; nn < 2; ++nn) {
      f32x4 h1v = acc1[m][nn], h3v = acc3[m][nn];
#pragma unroll
      for (int j = 0; j < 4; ++j) {
        float z = h1v[j];
        float val = (z / (1.f + expf(-z))) * h3v[j];
        int r = wr + m * 16 + (lane >> 4) * 4 + j;
        int c = wc + nn * 16 + fr;
        gated[gbase + (size_t)r * FF + c] = f2b(val);
      }
    }
  }
}

// -------- Down-proj + scatter: BK=64, 2-slot counted-vmcnt, 2 sub-phases --------
// Slot layout (bytes): A[0,16384) 128x64, B[16384,32768) 128x64.
__global__ __launch_bounds__(256) void down_kernel(
    const unsigned short* __restrict__ gated,
    const unsigned short* __restrict__ w2bf,
    const int* __restrict__ counts, const int* __restrict__ tokidx,
    const float* __restrict__ rww,
    float* __restrict__ final_out)
{
  int e = blockIdx.z;
  int n = counts[e];
  int row0 = blockIdx.y * 128;
  if (row0 >= n) return;
  int hbase = blockIdx.x * 128;
  int valid = min(128, n - row0);

  int pe = 0;
  for (int q = 0; q < e; ++q) pe += (counts[q] + 127) & ~127;

  __shared__ __align__(16) char lds[2 * LDSU];   // 64 KB

  int tid = threadIdx.x;
  int lane = tid & 63, wv = tid >> 6;
  int sb = (tid & 7) ^ ((tid >> 3) & 7);

  const unsigned short* ga[4];
  const unsigned short* gb[4];
#pragma unroll
  for (int j = 0; j < 4; ++j) {
    ga[j] = gated + ((size_t)pe + row0 + (tid >> 3) + 32 * j) * FF + sb * 8;
    gb[j] = w2bf + ((size_t)e * HH + hbase + (tid >> 3) + 32 * j) * FF + sb * 8;
  }

  int wr = (wv >> 1) * 64, wc = (wv & 1) * 64;
  int fr = lane & 15, kq = lane >> 4, l7 = lane & 7;

  f32x4 acc[4][4];
#pragma unroll
  for (int m = 0; m < 4; ++m)
#pragma unroll
    for (int nn = 0; nn < 4; ++nn) acc[m][nn] = (f32x4)0.f;

#define DN_STAGE(T, SOFF) do {                                                   \
    _Pragma("unroll") for (int j = 0; j < 4; ++j) {                              \
      gload16(ga[j] + (T) * 64, lds + (SOFF) + j * 4096 + wv * 1024);            \
      gload16(gb[j] + (T) * 64, lds + (SOFF) + 16384 + j * 4096 + wv * 1024);    \
    } } while (0)

#define DN_PHASE(SOFF, KS) do {                                                            \
    int bswz = (((KS) * 4 + kq) ^ l7) * 16;                                                \
    short8_t a[4], bf[4];                                                                  \
    _Pragma("unroll") for (int m = 0; m < 4; ++m)                                          \
      a[m] = *(const short8_t*)(lds + (SOFF) + (wr + m * 16 + fr) * 128 + bswz);           \
    _Pragma("unroll") for (int nn = 0; nn < 4; ++nn)                                       \
      bf[nn] = *(const short8_t*)(lds + (SOFF) + 16384 + (wc + nn * 16 + fr) * 128 + bswz); \
    __builtin_amdgcn_s_setprio(1);                                                         \
    _Pragma("unroll") for (int m = 0; m < 4; ++m)                                          \
      _Pragma("unroll") for (int nn = 0; nn < 4; ++nn)                                     \
        acc[m][nn] = __builtin_amdgcn_mfma_f32_16x16x32_bf16(a[m], bf[nn], acc[m][nn], 0, 0, 0); \
    __builtin_amdgcn_s_setprio(0);                                                         \
  } while (0)

#define DN_NT 32
#define DN_ITER(T, SOFF) do {                                          \
    if ((T) < DN_NT - 1) asm volatile("s_waitcnt vmcnt(8)" ::: "memory"); \
    else                 asm volatile("s_waitcnt vmcnt(0)" ::: "memory"); \
    __builtin_amdgcn_s_barrier(); FENCE;                               \
    DN_PHASE(SOFF, 0);                                                 \
    FENCE; __builtin_amdgcn_s_barrier(); FENCE;                        \
    DN_PHASE(SOFF, 1);                                                 \
    FENCE; __builtin_amdgcn_s_barrier(); FENCE;                        \
    if ((T) + 2 < DN_NT) DN_STAGE((T) + 2, SOFF);                      \
  } while (0)

  DN_STAGE(0, 0);
  DN_STAGE(1, LDSU);
  for (int t2 = 0; t2 < DN_NT; t2 += 2) { DN_ITER(t2, 0); DN_ITER(t2 + 1, LDSU); }
#undef DN_STAGE
#undef DN_PHASE
#undef DN_ITER

  // epilogue: final[t, h] += rw * out  (2 commutative f32 adds per element)
#pragma unroll
  for (int m = 0; m < 4; ++m) {
    int rbase = wr + m * 16 + (lane >> 4) * 4;
#pragma unroll
    for (int j = 0; j < 4; ++j) {
      int r = rbase + j;
      if (r < valid) {
        int t = tokidx[e * TT + row0 + r];
        float w = rww[e * TT + row0 + r];
#pragma unroll
        for (int nn = 0; nn < 4; ++nn) {
          int c = hbase + wc + nn * 16 + fr;
          atomicAdd(&final_out[(size_t)t * HH + c], w * acc[m][nn][j]);
        }
      }
    }
  }
}

extern "C" void kernel_launch(void* const* d_in, const int* in_sizes, int n_in,
                              void* d_out, int out_size, void* d_ws, size_t ws_size,
                              hipStream_t stream) {
  const float* x  = (const float*)d_in[0];   // [T, H]
  const float* gw = (const float*)d_in[1];   // [E, H]
  const float* w1 = (const float*)d_in[2];   // [E, F, H]
  const float* w2 = (const float*)d_in[3];   // [E, H, F]
  const float* w3 = (const float*)d_in[4];   // [E, F, H]

  float* final_out  = (float*)d_out;                       // [T, H]
  float* out_logits = final_out + (size_t)TT * HH;         // [T, E]

  char* ws = (char*)d_ws;
  int*    counts = (int*)(ws + 0);                            // 64 B
  int*    sel01  = (int*)(ws + 1024);                         // 16384
  float2* w01    = (float2*)(ws + 20480);                     // 32768
  int*    tokidx = (int*)(ws + 53248);                        // 131072
  float*  rww    = (float*)(ws + 184320);                     // 131072
  unsigned short* xbf   = (unsigned short*)(ws + 315392);     // 8388608
  unsigned short* w1bf  = (unsigned short*)(ws + 8704000);    // 33554432
  unsigned short* w3bf  = (unsigned short*)(ws + 42258432);   // 33554432
  unsigned short* gated = (unsigned short*)(ws + 75812864);   // 37748736
  const size_t base_end = 113561600;
  bool big = ws_size >= base_end + 33554432;                  // +32MB for w2bf
  unsigned short* w2bf = big ? (unsigned short*)(ws + base_end) : w1bf;

  int nconvblk = (big ? 3 : 2) * NC32;
  front_kernel<<<TT + nconvblk, 256, 0, stream>>>(
      x, gw, w1, w3, w2, out_logits, final_out, xbf, w1bf, w3bf, w2bf,
      sel01, w01);
  build_kernel<<<EE, 256, 0, stream>>>(sel01, w01, counts, tokidx, rww);
  up_gate_kernel<<<dim3(FF / 64, TT / 128, EE), 256, 0, stream>>>(
      xbf, w1bf, w3bf, counts, tokidx, gated);
  if (!big) conv_kernel<<<NC32, 256, 0, stream>>>(w2, w1bf);
  down_kernel<<<dim3(HH / 128, TT / 128, EE), 256, 0, stream>>>(
      gated, w2bf, counts, tokidx, rww, final_out);
}